// Round 7
// baseline (484.933 us; speedup 1.0000x reference)
//
#include <hip/hip_runtime.h>
#include <stdint.h>

typedef __attribute__((ext_vector_type(8))) short short8;
typedef __attribute__((ext_vector_type(4))) float floatx4;

__device__ __forceinline__ unsigned short f2bf(float x) {
    unsigned int u = __builtin_bit_cast(unsigned int, x);
    unsigned int r = (u + 0x7FFFu + ((u >> 16) & 1u)) >> 16;   // RNE
    return (unsigned short)r;
}

// tanh = (e^2x-1)/(e^2x+1), clamp |x|<=10; rcp + 1 Newton. ~1e-7 rel err.
__device__ __forceinline__ float fast_tanh(float x) {
    float xc = fminf(fmaxf(x, -10.0f), 10.0f);
    float e  = __expf(2.0f * xc);
    float d  = e + 1.0f;
    float r  = __builtin_amdgcn_rcpf(d);
    r = r * (2.0f - d * r);
    return (e - 1.0f) * r;
}

// ---- W f32 -> bf16 ----
__global__ void wconv(const float4* __restrict__ W4, ushort4* __restrict__ Wb4) {
    int i = blockIdx.x * 256 + threadIdx.x;
    float4 v = W4[i];
    ushort4 o;
    o.x = f2bf(v.x); o.y = f2bf(v.y); o.z = f2bf(v.z); o.w = f2bf(v.w);
    Wb4[i] = o;
}

// ---- level 0: h0 = bf16(tanh(emb[ids])), [131072][512], 8 elems/thread ----
__global__ void embed_tanh(const int* __restrict__ ids, const float* __restrict__ emb,
                           ushort* __restrict__ h0) {
    int idx = blockIdx.x * 256 + threadIdx.x;   // 8,388,608 threads
    int e = idx * 8;
    int row = e >> 9;
    int col = e & 511;
    int id = ids[row];
    const float* src = emb + (size_t)id * 512 + col;
    const float4 v0 = *reinterpret_cast<const float4*>(src);
    const float4 v1 = *reinterpret_cast<const float4*>(src + 4);
    short8 o;
    o[0] = (short)f2bf(fast_tanh(v0.x)); o[1] = (short)f2bf(fast_tanh(v0.y));
    o[2] = (short)f2bf(fast_tanh(v0.z)); o[3] = (short)f2bf(fast_tanh(v0.w));
    o[4] = (short)f2bf(fast_tanh(v1.x)); o[5] = (short)f2bf(fast_tanh(v1.y));
    o[6] = (short)f2bf(fast_tanh(v1.z)); o[7] = (short)f2bf(fast_tanh(v1.w));
    *reinterpret_cast<short8*>(h0 + e) = o;
}

// ======== shared GEMM-core macros (validated in rounds 3-4) ========
// 128x128 tile, BK=32, triple-buffered LDS, stage-2-ahead, counted vmcnt(4).
#define STAGE_(sA, sB, Ap, Bp, buf, k0)                                         \
    do {                                                                        \
        __builtin_amdgcn_global_load_lds(                                       \
            (const __attribute__((address_space(1))) void*)((Ap) + (k0)),       \
            (__attribute__((address_space(3))) void*)&sA[buf][tid * 8], 16, 0, 0); \
        __builtin_amdgcn_global_load_lds(                                       \
            (const __attribute__((address_space(1))) void*)((Ap) + 64 * 1024 + (k0)), \
            (__attribute__((address_space(3))) void*)&sA[buf][2048 + tid * 8], 16, 0, 0); \
        __builtin_amdgcn_global_load_lds(                                       \
            (const __attribute__((address_space(1))) void*)((Bp) + (k0)),       \
            (__attribute__((address_space(3))) void*)&sB[buf][tid * 8], 16, 0, 0); \
        __builtin_amdgcn_global_load_lds(                                       \
            (const __attribute__((address_space(1))) void*)((Bp) + 64 * 1024 + (k0)), \
            (__attribute__((address_space(3))) void*)&sB[buf][2048 + tid * 8], 16, 0, 0); \
    } while (0)

#define COMPUTE_(sA, sB, cur)                                                   \
    do {                                                                        \
        short8 a_[4], b_[4];                                                    \
        _Pragma("unroll")                                                       \
        for (int mi = 0; mi < 4; ++mi)                                          \
            a_[mi] = *reinterpret_cast<const short8*>(&sA[cur][(rA + mi * 16) * 32 + kksw]); \
        _Pragma("unroll")                                                       \
        for (int ni = 0; ni < 4; ++ni)                                          \
            b_[ni] = *reinterpret_cast<const short8*>(&sB[cur][(rB + ni * 16) * 32 + kksw]); \
        __builtin_amdgcn_s_setprio(1);                                          \
        _Pragma("unroll")                                                       \
        for (int mi = 0; mi < 4; ++mi)                                          \
            _Pragma("unroll")                                                   \
            for (int ni = 0; ni < 4; ++ni)                                      \
                acc[mi][ni] = __builtin_amdgcn_mfma_f32_16x16x32_bf16(          \
                    a_[mi], b_[ni], acc[mi][ni], 0, 0, 0);                      \
        __builtin_amdgcn_s_setprio(0);                                          \
    } while (0)

#define KLOOP_(sA, sB, Ap, Bp)                                                  \
    do {                                                                        \
        STAGE_(sA, sB, Ap, Bp, 0, 0);                                           \
        STAGE_(sA, sB, Ap, Bp, 1, 32);                                          \
        for (int t = 0; t < 30; t += 3) {                                       \
            asm volatile("s_barrier" ::: "memory");                             \
            STAGE_(sA, sB, Ap, Bp, 2, (t + 2) * 32);                            \
            asm volatile("s_waitcnt vmcnt(4)" ::: "memory");                    \
            COMPUTE_(sA, sB, 0);                                                \
            asm volatile("s_barrier" ::: "memory");                             \
            STAGE_(sA, sB, Ap, Bp, 0, (t + 3) * 32);                            \
            asm volatile("s_waitcnt vmcnt(4)" ::: "memory");                    \
            COMPUTE_(sA, sB, 1);                                                \
            asm volatile("s_barrier" ::: "memory");                             \
            STAGE_(sA, sB, Ap, Bp, 1, (t + 4) * 32);                            \
            asm volatile("s_waitcnt vmcnt(4)" ::: "memory");                    \
            COMPUTE_(sA, sB, 2);                                                \
        }                                                                       \
        asm volatile("s_barrier" ::: "memory");                                 \
        asm volatile("s_waitcnt vmcnt(0)" ::: "memory");                        \
        COMPUTE_(sA, sB, 0);                                                    \
        asm volatile("s_barrier" ::: "memory");                                 \
        asm volatile("s_waitcnt vmcnt(0)" ::: "memory");                        \
        COMPUTE_(sA, sB, 1);                                                    \
    } while (0)

// ---- levels 1..5: out[M][512] = tanh(A[M][1024] @ W^T + b), M >= 4096 ----
__global__ __launch_bounds__(256)
void level_gemm(const ushort* __restrict__ A, const ushort* __restrict__ Bt,
                const float* __restrict__ bias,
                ushort* __restrict__ outb, int M)
{
    const int nb  = gridDim.x;
    int bid = blockIdx.x;
    const int per = nb >> 3;                       // nb always multiple of 8 here
    const int lin = (bid & 7) * per + (bid >> 3);  // bijective XCD chunking
    const int mt = lin >> 2, nt = lin & 3;
    const int m0 = mt * 128, n0 = nt * 128;

    __shared__ alignas(16) ushort sA[3][4096];
    __shared__ alignas(16) ushort sB[3][4096];

    const int tid  = threadIdx.x;
    const int lane = tid & 63;
    const int w    = tid >> 6;
    const int wr   = w >> 1, wc = w & 1;

    const int sr    = tid >> 2;
    const int swcol = (((tid & 3) ^ ((tid >> 3) & 3)) << 3);
    const ushort* Ap = A  + (size_t)(m0 + sr) * 1024 + swcol;
    const ushort* Bp = Bt + (size_t)(n0 + sr) * 1024 + swcol;

    const int rA   = wr * 64 + (lane & 15);
    const int rB   = wc * 64 + (lane & 15);
    const int kksw = (((lane >> 4) ^ ((lane >> 1) & 3)) << 3);

    floatx4 acc[4][4] = {};
    KLOOP_(sA, sB, Ap, Bp);

    const int mrow = (lane >> 4) * 4;
    const int ncol = lane & 15;
    #pragma unroll
    for (int mi = 0; mi < 4; ++mi) {
        #pragma unroll
        for (int ni = 0; ni < 4; ++ni) {
            const int n = n0 + wc * 64 + ni * 16 + ncol;
            const float bb = bias[n];
            #pragma unroll
            for (int j = 0; j < 4; ++j) {
                const int m = m0 + wr * 64 + mi * 16 + mrow + j;
                float v = fast_tanh(acc[mi][ni][j] + bb);
                outb[(size_t)m * 512 + n] = f2bf(v);
            }
        }
    }
}

// ---- software grid barrier (Guideline 16: device-scope atomics + fences) ----
__device__ __forceinline__ void grid_bar(unsigned* bar, unsigned target) {
    __syncthreads();
    if (threadIdx.x == 0) {
        __threadfence();   // release: my stores visible before arrival
        __hip_atomic_fetch_add(bar, 1u, __ATOMIC_RELEASE, __HIP_MEMORY_SCOPE_AGENT);
        while (__hip_atomic_load(bar, __ATOMIC_ACQUIRE, __HIP_MEMORY_SCOPE_AGENT) < target)
            __builtin_amdgcn_s_sleep(1);
        __threadfence();   // acquire: others' stores visible after release
    }
    __syncthreads();
}

// ---- levels 6..11 fused, one launch: 64 blocks, grid barrier between levels.
// Per level M = 2048,1024,512,256,128,64; tiles = ceil(M/128)*4; idle blocks
// just hit the barrier. Same validated 128x128 GEMM core as level_gemm.
// lev0 reads hB (level-5 output), then ping-pong hA/hB.
__global__ __launch_bounds__(256)
void tail6(const ushort* __restrict__ Bt, const float* __restrict__ bias,
           ushort* __restrict__ hA, ushort* __restrict__ hB,
           float* __restrict__ out, unsigned* bar)
{
    __shared__ alignas(16) ushort sA[3][4096];
    __shared__ alignas(16) ushort sB[3][4096];

    const int tid  = threadIdx.x;
    const int lane = tid & 63;
    const int w    = tid >> 6;
    const int wr   = w >> 1, wc = w & 1;
    const int bid  = blockIdx.x;

    const int sr    = tid >> 2;
    const int swcol = (((tid & 3) ^ ((tid >> 3) & 3)) << 3);
    const int rA    = wr * 64 + (lane & 15);
    const int rB    = wc * 64 + (lane & 15);
    const int kksw  = (((lane >> 4) ^ ((lane >> 1) & 3)) << 3);
    const int mrow  = (lane >> 4) * 4;
    const int ncol  = lane & 15;

    int M = 2048;
    for (int lev = 0; lev < 6; ++lev, M >>= 1) {
        const ushort* src = (lev & 1) ? hA : hB;
        ushort*       dst = (lev & 1) ? hB : hA;
        const int T = ((M + 127) >> 7) * 4;
        if (bid < T) {
            const int mt = bid >> 2, nt = bid & 3;
            const int m0 = mt * 128, n0 = nt * 128;
            const ushort* Ap = src + (size_t)(m0 + sr) * 1024 + swcol;
            const ushort* Bp = Bt  + (size_t)(n0 + sr) * 1024 + swcol;

            floatx4 acc[4][4] = {};
            KLOOP_(sA, sB, Ap, Bp);

            #pragma unroll
            for (int mi = 0; mi < 4; ++mi) {
                #pragma unroll
                for (int ni = 0; ni < 4; ++ni) {
                    const int n = n0 + wc * 64 + ni * 16 + ncol;
                    const float bb = bias[n];
                    #pragma unroll
                    for (int j = 0; j < 4; ++j) {
                        const int m = m0 + wr * 64 + mi * 16 + mrow + j;
                        if (m < M) {
                            float v = fast_tanh(acc[mi][ni][j] + bb);
                            if (lev == 5) out[(size_t)m * 512 + n] = v;  // roots, f32
                            else          dst[(size_t)m * 512 + n] = f2bf(v);
                        }
                    }
                }
            }
        }
        if (lev < 5) grid_bar(bar, (unsigned)((lev + 1) * gridDim.x));
    }
}

extern "C" void kernel_launch(void* const* d_in, const int* in_sizes, int n_in,
                              void* d_out, int out_size, void* d_ws, size_t ws_size,
                              hipStream_t stream) {
    const int*   ids  = (const int*)d_in[0];
    const float* emb  = (const float*)d_in[1];
    const float* W    = (const float*)d_in[2];
    const float* bias = (const float*)d_in[3];
    float* out = (float*)d_out;

    unsigned short* Wb = (unsigned short*)d_ws;        // 1 MiB
    unsigned short* hA = Wb + 524288;                  // 128 MiB region
    unsigned short* hB = hA + 67108864;                // 64 MiB region
    // bar lives at hB+32MiB: written by level 1 (which covers all of hB), so it
    // must be zeroed AFTER level 5 and BEFORE tail6 (stream-ordered memset).
    // During tail6, hB writes are only lev1 (1 MiB) / lev3 (0.25 MiB) -> safe.
    unsigned* bar = (unsigned*)(hB + 16777216);

    wconv<<<512, 256, 0, stream>>>((const float4*)W, (ushort4*)Wb);
    embed_tanh<<<32768, 256, 0, stream>>>(ids, emb, hA);

    int M = 65536;
    for (int l = 1; l <= 5; ++l) {                     // outputs: hB,hA,hB,hA,hB
        const unsigned short* in = (l & 1) ? hA : hB;
        unsigned short*       ob = (l & 1) ? hB : hA;
        int gm = M / 128;
        level_gemm<<<gm * 4, 256, 0, stream>>>(in, Wb, bias, ob, M);
        M >>= 1;
    }
    (void)hipMemsetAsync((void*)bar, 0, 4, stream);    // zero AFTER lev5 writes hB
    tail6<<<64, 256, 0, stream>>>(Wb, bias, hA, hB, out, bar);  // levels 6..11
}

// Round 8
// 441.442 us; speedup vs baseline: 1.0985x; 1.0985x over previous
//
#include <hip/hip_runtime.h>
#include <stdint.h>

typedef __attribute__((ext_vector_type(8))) short short8;
typedef __attribute__((ext_vector_type(4))) float floatx4;

__device__ __forceinline__ unsigned short f2bf(float x) {
    unsigned int u = __builtin_bit_cast(unsigned int, x);
    unsigned int r = (u + 0x7FFFu + ((u >> 16) & 1u)) >> 16;   // RNE
    return (unsigned short)r;
}

// tanh = (e^2x-1)/(e^2x+1), clamp |x|<=10; rcp + 1 Newton. ~1e-7 rel err.
__device__ __forceinline__ float fast_tanh(float x) {
    float xc = fminf(fmaxf(x, -10.0f), 10.0f);
    float e  = __expf(2.0f * xc);
    float d  = e + 1.0f;
    float r  = __builtin_amdgcn_rcpf(d);
    r = r * (2.0f - d * r);
    return (e - 1.0f) * r;
}

// ---- W f32 -> bf16 ----
__global__ void wconv(const float4* __restrict__ W4, ushort4* __restrict__ Wb4) {
    int i = blockIdx.x * 256 + threadIdx.x;
    float4 v = W4[i];
    ushort4 o;
    o.x = f2bf(v.x); o.y = f2bf(v.y); o.z = f2bf(v.z); o.w = f2bf(v.w);
    Wb4[i] = o;
}

// ---- level 0: h0 = bf16(tanh(emb[ids])), [131072][512], 8 elems/thread ----
__global__ void embed_tanh(const int* __restrict__ ids, const float* __restrict__ emb,
                           ushort* __restrict__ h0) {
    int idx = blockIdx.x * 256 + threadIdx.x;   // 8,388,608 threads
    int e = idx * 8;
    int row = e >> 9;
    int col = e & 511;
    int id = ids[row];
    const float* src = emb + (size_t)id * 512 + col;
    const float4 v0 = *reinterpret_cast<const float4*>(src);
    const float4 v1 = *reinterpret_cast<const float4*>(src + 4);
    short8 o;
    o[0] = (short)f2bf(fast_tanh(v0.x)); o[1] = (short)f2bf(fast_tanh(v0.y));
    o[2] = (short)f2bf(fast_tanh(v0.z)); o[3] = (short)f2bf(fast_tanh(v0.w));
    o[4] = (short)f2bf(fast_tanh(v1.x)); o[5] = (short)f2bf(fast_tanh(v1.y));
    o[6] = (short)f2bf(fast_tanh(v1.z)); o[7] = (short)f2bf(fast_tanh(v1.w));
    *reinterpret_cast<short8*>(h0 + e) = o;
}

// ======== shared GEMM-core macros ========
#define STAGE_(sA, sB, Ap, Bp, buf, k0)                                         \
    do {                                                                        \
        __builtin_amdgcn_global_load_lds(                                       \
            (const __attribute__((address_space(1))) void*)((Ap) + (k0)),       \
            (__attribute__((address_space(3))) void*)&sA[buf][tid * 8], 16, 0, 0); \
        __builtin_amdgcn_global_load_lds(                                       \
            (const __attribute__((address_space(1))) void*)((Ap) + 64 * 1024 + (k0)), \
            (__attribute__((address_space(3))) void*)&sA[buf][2048 + tid * 8], 16, 0, 0); \
        __builtin_amdgcn_global_load_lds(                                       \
            (const __attribute__((address_space(1))) void*)((Bp) + (k0)),       \
            (__attribute__((address_space(3))) void*)&sB[buf][tid * 8], 16, 0, 0); \
        __builtin_amdgcn_global_load_lds(                                       \
            (const __attribute__((address_space(1))) void*)((Bp) + 64 * 1024 + (k0)), \
            (__attribute__((address_space(3))) void*)&sB[buf][2048 + tid * 8], 16, 0, 0); \
    } while (0)

#define COMPUTE_(sA, sB, cur)                                                   \
    do {                                                                        \
        short8 a_[4], b_[4];                                                    \
        _Pragma("unroll")                                                       \
        for (int mi = 0; mi < 4; ++mi)                                          \
            a_[mi] = *reinterpret_cast<const short8*>(&sA[cur][(rA + mi * 16) * 32 + kksw]); \
        _Pragma("unroll")                                                       \
        for (int ni = 0; ni < 4; ++ni)                                          \
            b_[ni] = *reinterpret_cast<const short8*>(&sB[cur][(rB + ni * 16) * 32 + kksw]); \
        __builtin_amdgcn_s_setprio(1);                                          \
        _Pragma("unroll")                                                       \
        for (int mi = 0; mi < 4; ++mi)                                          \
            _Pragma("unroll")                                                   \
            for (int ni = 0; ni < 4; ++ni)                                      \
                acc[mi][ni] = __builtin_amdgcn_mfma_f32_16x16x32_bf16(          \
                    a_[mi], b_[ni], acc[mi][ni], 0, 0, 0);                      \
        __builtin_amdgcn_s_setprio(0);                                          \
    } while (0)

// ---- validated round-3 loop (1-deep, barrier-first): used by level_gemm ----
#define KLOOP_(sA, sB, Ap, Bp)                                                  \
    do {                                                                        \
        STAGE_(sA, sB, Ap, Bp, 0, 0);                                           \
        STAGE_(sA, sB, Ap, Bp, 1, 32);                                          \
        for (int t = 0; t < 30; t += 3) {                                       \
            asm volatile("s_barrier" ::: "memory");                             \
            STAGE_(sA, sB, Ap, Bp, 2, (t + 2) * 32);                            \
            asm volatile("s_waitcnt vmcnt(4)" ::: "memory");                    \
            COMPUTE_(sA, sB, 0);                                                \
            asm volatile("s_barrier" ::: "memory");                             \
            STAGE_(sA, sB, Ap, Bp, 0, (t + 3) * 32);                            \
            asm volatile("s_waitcnt vmcnt(4)" ::: "memory");                    \
            COMPUTE_(sA, sB, 1);                                                \
            asm volatile("s_barrier" ::: "memory");                             \
            STAGE_(sA, sB, Ap, Bp, 1, (t + 4) * 32);                            \
            asm volatile("s_waitcnt vmcnt(4)" ::: "memory");                    \
            COMPUTE_(sA, sB, 2);                                                \
        }                                                                       \
        asm volatile("s_barrier" ::: "memory");                                 \
        asm volatile("s_waitcnt vmcnt(0)" ::: "memory");                        \
        COMPUTE_(sA, sB, 0);                                                    \
        asm volatile("s_barrier" ::: "memory");                                 \
        asm volatile("s_waitcnt vmcnt(0)" ::: "memory");                        \
        COMPUTE_(sA, sB, 1);                                                    \
    } while (0)

// ---- levels 1..5: out[M][512] = tanh(A[M][1024] @ W^T + b), M >= 4096 ----
__global__ __launch_bounds__(256)
void level_gemm(const ushort* __restrict__ A, const ushort* __restrict__ Bt,
                const float* __restrict__ bias,
                ushort* __restrict__ outb, int M)
{
    const int nb  = gridDim.x;
    int bid = blockIdx.x;
    const int per = nb >> 3;                       // nb always multiple of 8 here
    const int lin = (bid & 7) * per + (bid >> 3);  // bijective XCD chunking
    const int mt = lin >> 2, nt = lin & 3;
    const int m0 = mt * 128, n0 = nt * 128;

    __shared__ alignas(16) ushort sA[3][4096];
    __shared__ alignas(16) ushort sB[3][4096];

    const int tid  = threadIdx.x;
    const int lane = tid & 63;
    const int w    = tid >> 6;
    const int wr   = w >> 1, wc = w & 1;

    const int sr    = tid >> 2;
    const int swcol = (((tid & 3) ^ ((tid >> 3) & 3)) << 3);
    const ushort* Ap = A  + (size_t)(m0 + sr) * 1024 + swcol;
    const ushort* Bp = Bt + (size_t)(n0 + sr) * 1024 + swcol;

    const int rA   = wr * 64 + (lane & 15);
    const int rB   = wc * 64 + (lane & 15);
    const int kksw = (((lane >> 4) ^ ((lane >> 1) & 3)) << 3);

    floatx4 acc[4][4] = {};
    KLOOP_(sA, sB, Ap, Bp);

    const int mrow = (lane >> 4) * 4;
    const int ncol = lane & 15;
    #pragma unroll
    for (int mi = 0; mi < 4; ++mi) {
        #pragma unroll
        for (int ni = 0; ni < 4; ++ni) {
            const int n = n0 + wc * 64 + ni * 16 + ncol;
            const float bb = bias[n];
            #pragma unroll
            for (int j = 0; j < 4; ++j) {
                const int m = m0 + wr * 64 + mi * 16 + mrow + j;
                float v = fast_tanh(acc[mi][ni][j] + bb);
                outb[(size_t)m * 512 + n] = f2bf(v);
            }
        }
    }
}

// ---- software grid barrier: relaxed spin (NO per-iteration acquire — an
// agent-acquire load emits buffer_inv, and 60 spinning blocks nuking all 8
// XCD L2s every ~64cy was round-7's 202us). One fence after exit.
__device__ __forceinline__ void grid_bar(unsigned* bar, unsigned target, bool did_work) {
    __syncthreads();   // emits vmcnt(0) drain: this block's stores are in L2
    if (threadIdx.x == 0) {
        if (did_work) {
            __threadfence();   // release: flush this XCD's L2 so others see stores
            __hip_atomic_fetch_add(bar, 1u, __ATOMIC_RELEASE, __HIP_MEMORY_SCOPE_AGENT);
        } else {
            __hip_atomic_fetch_add(bar, 1u, __ATOMIC_RELAXED, __HIP_MEMORY_SCOPE_AGENT);
        }
        while (__hip_atomic_load(bar, __ATOMIC_RELAXED, __HIP_MEMORY_SCOPE_AGENT) < target)
            __builtin_amdgcn_s_sleep(2);
        __threadfence();   // acquire once: invalidate stale lines before next level
    }
    __syncthreads();
}

// ---- levels 6..11 fused: 64 blocks, grid barrier between levels.
// Latency-bound (1 block/CU): depth-4 prefetch, 6 LDS buffers (96 KiB).
// Per iter: STAGE(t+4) -> vmcnt(16) -> s_barrier -> compute(t).
// Ledger: own tile-t loads retired pre-barrier => cross-wave reads safe;
// staged buf (t+4)%6 last read at iter t-2, separated by barrier t-1 => WAR safe.
__global__ __launch_bounds__(256)
void tail6(const ushort* __restrict__ Bt, const float* __restrict__ bias,
           ushort* __restrict__ hA, ushort* __restrict__ hB,
           float* __restrict__ out, unsigned* bar)
{
    __shared__ alignas(16) ushort sA[6][4096];
    __shared__ alignas(16) ushort sB[6][4096];

    const int tid  = threadIdx.x;
    const int lane = tid & 63;
    const int w    = tid >> 6;
    const int wr   = w >> 1, wc = w & 1;
    const int bid  = blockIdx.x;

    const int sr    = tid >> 2;
    const int swcol = (((tid & 3) ^ ((tid >> 3) & 3)) << 3);
    const int rA    = wr * 64 + (lane & 15);
    const int rB    = wc * 64 + (lane & 15);
    const int kksw  = (((lane >> 4) ^ ((lane >> 1) & 3)) << 3);
    const int mrow  = (lane >> 4) * 4;
    const int ncol  = lane & 15;

    int M = 2048;
    for (int lev = 0; lev < 6; ++lev, M >>= 1) {
        const ushort* src = (lev & 1) ? hA : hB;
        ushort*       dst = (lev & 1) ? hB : hA;
        const int T = ((M + 127) >> 7) * 4;
        const bool work = (bid < T);
        if (work) {
            const int mt = bid >> 2, nt = bid & 3;
            const int m0 = mt * 128, n0 = nt * 128;
            const ushort* Ap = src + (size_t)(m0 + sr) * 1024 + swcol;
            const ushort* Bp = Bt  + (size_t)(n0 + sr) * 1024 + swcol;

            floatx4 acc[4][4] = {};

            STAGE_(sA, sB, Ap, Bp, 0, 0);
            STAGE_(sA, sB, Ap, Bp, 1, 32);
            STAGE_(sA, sB, Ap, Bp, 2, 64);
            STAGE_(sA, sB, Ap, Bp, 3, 96);
            for (int t = 0; t < 28; ++t) {
                const int sb = (t + 4) % 6;
                STAGE_(sA, sB, Ap, Bp, sb, (t + 4) * 32);
                asm volatile("s_waitcnt vmcnt(16)" ::: "memory");  // retire tile t
                asm volatile("s_barrier" ::: "memory");
                const int cb = t % 6;
                COMPUTE_(sA, sB, cb);
            }
            // drains: t=28..31, outstanding 16 -> 0
            for (int t = 28; t < 32; ++t) {
                switch (31 - t) {
                    case 3: asm volatile("s_waitcnt vmcnt(12)" ::: "memory"); break;
                    case 2: asm volatile("s_waitcnt vmcnt(8)"  ::: "memory"); break;
                    case 1: asm volatile("s_waitcnt vmcnt(4)"  ::: "memory"); break;
                    default: asm volatile("s_waitcnt vmcnt(0)" ::: "memory"); break;
                }
                asm volatile("s_barrier" ::: "memory");
                COMPUTE_(sA, sB, t % 6);
            }

            #pragma unroll
            for (int mi = 0; mi < 4; ++mi) {
                #pragma unroll
                for (int ni = 0; ni < 4; ++ni) {
                    const int n = n0 + wc * 64 + ni * 16 + ncol;
                    const float bb = bias[n];
                    #pragma unroll
                    for (int j = 0; j < 4; ++j) {
                        const int m = m0 + wr * 64 + mi * 16 + mrow + j;
                        if (m < M) {
                            float v = fast_tanh(acc[mi][ni][j] + bb);
                            if (lev == 5) out[(size_t)m * 512 + n] = v;  // roots, f32
                            else          dst[(size_t)m * 512 + n] = f2bf(v);
                        }
                    }
                }
            }
        }
        if (lev < 5) grid_bar(bar, (unsigned)((lev + 1) * gridDim.x), work);
    }
}

extern "C" void kernel_launch(void* const* d_in, const int* in_sizes, int n_in,
                              void* d_out, int out_size, void* d_ws, size_t ws_size,
                              hipStream_t stream) {
    const int*   ids  = (const int*)d_in[0];
    const float* emb  = (const float*)d_in[1];
    const float* W    = (const float*)d_in[2];
    const float* bias = (const float*)d_in[3];
    float* out = (float*)d_out;

    unsigned short* Wb = (unsigned short*)d_ws;        // 1 MiB
    unsigned short* hA = Wb + 524288;                  // 128 MiB region
    unsigned short* hB = hA + 67108864;                // 64 MiB region
    // bar at hB+32MiB: clobbered by level-1 writes, so zero it AFTER level 5
    // (stream-ordered) and before tail6. tail6 writes at most hB+1MiB. Safe.
    unsigned* bar = (unsigned*)(hB + 16777216);

    wconv<<<512, 256, 0, stream>>>((const float4*)W, (ushort4*)Wb);
    embed_tanh<<<32768, 256, 0, stream>>>(ids, emb, hA);

    int M = 65536;
    for (int l = 1; l <= 5; ++l) {                     // outputs: hB,hA,hB,hA,hB
        const unsigned short* in = (l & 1) ? hA : hB;
        unsigned short*       ob = (l & 1) ? hB : hA;
        int gm = M / 128;
        level_gemm<<<gm * 4, 256, 0, stream>>>(in, Wb, bias, ob, M);
        M >>= 1;
    }
    (void)hipMemsetAsync((void*)bar, 0, 4, stream);    // zero AFTER lev5 writes hB
    tail6<<<64, 256, 0, stream>>>(Wb, bias, hA, hB, out, bar);  // levels 6..11
}